// Round 10
// baseline (18.519 us; speedup 1.0000x reference)
//
#include <hip/hip_runtime.h>
#include <stdint.h>

#define NB 64      // batch rows
#define NK 1024    // keys
#define ND 512     // dim
#define CHUNKS 64                               // key chunks
#define KPB (NK / CHUNKS)                       // 16 keys per block
#define RPB 4                                   // rows per block (1 per wave)
#define RGROUPS (NB / RPB)                      // 16 row groups
// ws layout: u64 packed winner per (row, chunk): [NB][CHUNKS]

#if __has_builtin(__builtin_amdgcn_exp2f)
#define EXP2F(x) __builtin_amdgcn_exp2f(x)
#else
#define EXP2F(x) exp2f(x)
#endif
#if __has_builtin(__builtin_amdgcn_rcpf)
#define RCPF(x) __builtin_amdgcn_rcpf(x)
#else
#define RCPF(x) (1.0f / (x))
#endif

// u * sigmoid(u + 1) accumulated into acc; key element pre-masked.
__device__ __forceinline__ float silu_acc(float qc, float kz, float acc) {
    float u = qc * kz;
    const float NL2E = -1.4426950408889634f;
    float y = fmaf(u, NL2E, NL2E);      // -(u+1)*log2e
    float e = EXP2F(y);
    float r = RCPF(1.0f + e);
    return fmaf(u, r, acc);
}

// pack: [sortable_score:32][..][1023-k:10]. max() picks best score; on exact
// score ties larger (1023-k) => smaller k wins (numpy argmax first-occurrence).
__device__ __forceinline__ unsigned long long pack_win(float s, int k) {
    uint32_t bits = __float_as_uint(s);
    uint32_t so = (bits & 0x80000000u) ? ~bits : (bits | 0x80000000u);
    return ((unsigned long long)so << 32) | (unsigned long long)(uint32_t)(NK - 1 - k);
}

__device__ __forceinline__ float msk(float kv) {
    return (fabsf(kv) > 1e-6f) ? kv : 0.0f;
}

__global__ __launch_bounds__(256) void sia_scores(const float* __restrict__ q,
                                                  const float* __restrict__ keys,
                                                  unsigned long long* __restrict__ ws) {
    const int bidx = blockIdx.x;            // 0 .. 1023
    const int rg    = bidx >> 6;            // row group 0..15
    const int chunk = bidx & (CHUNKS - 1);  // 0..63 (chunk&7 == bidx&7: natural XCD affinity)
    const int tid = threadIdx.x;
    const int wave = tid >> 6;
    const int lane = tid & 63;

    const float C = 100.0f * 0.04419417382415922f;   // SCALE * D^-0.5

    // ---- stage this chunk's 16 keys into LDS, mask folded in (once per byte) ----
    __shared__ float kls[KPB * ND];         // 32KB
    {
        const float4* gk = reinterpret_cast<const float4*>(keys + (size_t)chunk * KPB * ND);
        float4* lk = reinterpret_cast<float4*>(kls);
        #pragma unroll
        for (int i = 0; i < (KPB * ND / 4) / 256; ++i) {   // 8 iters
            float4 v = gk[i * 256 + tid];
            v.x = msk(v.x); v.y = msk(v.y); v.z = msk(v.z); v.w = msk(v.w);
            lk[i * 256 + tid] = v;
        }
    }
    __syncthreads();

    // ---- each wave: one batch row vs all 16 keys ----
    const int row = rg * RPB + wave;
    const float4* q4 = reinterpret_cast<const float4*>(q + row * ND + lane * 8);
    float4 qa = q4[0];
    float4 qb = q4[1];
    qa.x *= C; qa.y *= C; qa.z *= C; qa.w *= C;
    qb.x *= C; qb.y *= C; qb.z *= C; qb.w *= C;

    float acc[KPB];
    #pragma unroll
    for (int kk = 0; kk < KPB; ++kk) {
        const float4* k4 = reinterpret_cast<const float4*>(&kls[kk * ND + lane * 8]);
        float4 ka = k4[0];
        float4 kb = k4[1];
        float p = 0.0f;
        p = silu_acc(qa.x, ka.x, p);
        p = silu_acc(qa.y, ka.y, p);
        p = silu_acc(qa.z, ka.z, p);
        p = silu_acc(qa.w, ka.w, p);
        p = silu_acc(qb.x, kb.x, p);
        p = silu_acc(qb.y, kb.y, p);
        p = silu_acc(qb.z, kb.z, p);
        p = silu_acc(qb.w, kb.w, p);
        acc[kk] = p;
    }

    // batched butterfly reduce: 16 independent values per step
    #pragma unroll
    for (int off = 32; off > 0; off >>= 1) {
        #pragma unroll
        for (int kk = 0; kk < KPB; ++kk)
            acc[kk] += __shfl_xor(acc[kk], off, 64);
    }

    // per-wave argmax over its 16 keys (strict >: earliest key wins ties);
    // waves own disjoint rows -> direct store, no cross-wave reduce.
    if (lane == 0) {
        float best_s = acc[0];
        int best_j = 0;
        #pragma unroll
        for (int kk = 1; kk < KPB; ++kk)
            if (acc[kk] > best_s) { best_s = acc[kk]; best_j = kk; }
        ws[row * CHUNKS + chunk] = pack_win(best_s, chunk * KPB + best_j);
    }
}

__global__ __launch_bounds__(64) void sia_final(const unsigned long long* __restrict__ ws,
                                                const float* __restrict__ values,
                                                float* __restrict__ out) {
    const int b = blockIdx.x;
    const int lane = threadIdx.x;

    unsigned long long p = ws[b * CHUNKS + lane];
    #pragma unroll
    for (int off = 32; off > 0; off >>= 1) {
        unsigned long long o = __shfl_xor(p, off, 64);
        if (o > p) p = o;
    }
    const int k = NK - 1 - (int)((uint32_t)p & 0x3FFu);

    // gather winner's values row: 64 lanes x 8 floats
    const float4* v4 = reinterpret_cast<const float4*>(values + (size_t)k * ND) + lane * 2;
    float4* o4 = reinterpret_cast<float4*>(out + b * ND) + lane * 2;
    o4[0] = v4[0];
    o4[1] = v4[1];

    if (lane == 0)
        out[NB * ND + b] = (float)k;   // winner_idx, read back as float32
}

extern "C" void kernel_launch(void* const* d_in, const int* in_sizes, int n_in,
                              void* d_out, int out_size, void* d_ws, size_t ws_size,
                              hipStream_t stream) {
    const float* q      = (const float*)d_in[0];   // [64, 512]
    const float* keys   = (const float*)d_in[1];   // [1024, 512]
    const float* values = (const float*)d_in[2];   // [1024, 512]
    float* out = (float*)d_out;                    // 64*512 values then 64 idx
    unsigned long long* ws = (unsigned long long*)d_ws;

    sia_scores<<<dim3(RGROUPS * CHUNKS), dim3(256), 0, stream>>>(q, keys, ws);
    sia_final<<<dim3(NB), dim3(64), 0, stream>>>(ws, values, out);
}